// Round 8
// baseline (683.697 us; speedup 1.0000x reference)
//
#include <hip/hip_runtime.h>

#define NTOK 8192
#define DDIM 1024
#define HDIM 2048
#define NEXP 8
#define GEXP 2                  // experts per group (h' = 67 MB, L3-resident)

typedef unsigned short u16;
typedef short bf16x8 __attribute__((ext_vector_type(8)));
typedef float f32x4 __attribute__((ext_vector_type(4)));
typedef float float4_t __attribute__((ext_vector_type(4)));

__device__ __forceinline__ u16 f2bf(float f) {
  unsigned u = __float_as_uint(f);
  u += 0x7FFFu + ((u >> 16) & 1u);   // round-to-nearest-even
  return (u16)(u >> 16);
}

#define GLOAD_LDS16(gp, lp)                                                     \
  __builtin_amdgcn_global_load_lds(                                             \
      (const __attribute__((address_space(1))) unsigned int*)(gp),              \
      (__attribute__((address_space(3))) unsigned int*)(lp), 16, 0, 0)

// ------------------------------------------------ fused x->bf16 convert + gate
__global__ void k_prep(const float* __restrict__ x, const float* __restrict__ Wg,
                       const float* __restrict__ bg,
                       u16* __restrict__ xb, float* __restrict__ gate) {
  const int tok = (blockIdx.x * 256 + threadIdx.x) >> 6;
  const int lane = threadIdx.x & 63;
  const float* xr = x + (size_t)tok * DDIM;
  u16* xo = xb + (size_t)tok * DDIM;
  float s[NEXP];
#pragma unroll
  for (int e = 0; e < NEXP; ++e) s[e] = 0.f;
#pragma unroll
  for (int it = 0; it < 2; ++it) {
    const int d0 = lane * 8 + it * 512;
    float4_t v0 = *(const float4_t*)(xr + d0);
    float4_t v1 = *(const float4_t*)(xr + d0 + 4);
    union { bf16x8 v; u16 h[8]; } u;
    u.h[0] = f2bf(v0.x); u.h[1] = f2bf(v0.y); u.h[2] = f2bf(v0.z); u.h[3] = f2bf(v0.w);
    u.h[4] = f2bf(v1.x); u.h[5] = f2bf(v1.y); u.h[6] = f2bf(v1.z); u.h[7] = f2bf(v1.w);
    *(bf16x8*)(xo + d0) = u.v;
    float xv[8] = {v0.x, v0.y, v0.z, v0.w, v1.x, v1.y, v1.z, v1.w};
#pragma unroll
    for (int j = 0; j < 8; ++j) {
      const float4_t w0 = *(const float4_t*)(Wg + (size_t)(d0 + j) * NEXP);
      const float4_t w1 = *(const float4_t*)(Wg + (size_t)(d0 + j) * NEXP + 4);
      s[0] += xv[j] * w0.x; s[1] += xv[j] * w0.y;
      s[2] += xv[j] * w0.z; s[3] += xv[j] * w0.w;
      s[4] += xv[j] * w1.x; s[5] += xv[j] * w1.y;
      s[6] += xv[j] * w1.z; s[7] += xv[j] * w1.w;
    }
  }
#pragma unroll
  for (int off = 32; off; off >>= 1)
#pragma unroll
    for (int e = 0; e < NEXP; ++e) s[e] += __shfl_down(s[e], off);
  if (lane == 0) {
#pragma unroll
    for (int e = 0; e < NEXP; ++e) gate[(size_t)tok * NEXP + e] = s[e] + bg[e];
  }
}

// ------------- vectorized transpose+convert: out[z*oexp + c*orstride + r] = in[z][r][c]
__global__ void k_transpose(const float* __restrict__ in, u16* __restrict__ out,
                            int R, int C, size_t oexp, int orstride) {
  __shared__ float t[64][65];
  const int rb = blockIdx.x * 64, cb = blockIdx.y * 64;
  const float* pin = in + (size_t)blockIdx.z * R * C;
  u16* pout = out + (size_t)blockIdx.z * oexp;
  const int tid = threadIdx.x;
  {
    const int r = tid >> 4;
    const int c4 = (tid & 15) * 4;
#pragma unroll
    for (int i = 0; i < 4; ++i) {
      float4_t v = *(const float4_t*)(pin + (size_t)(rb + r + 16 * i) * C + cb + c4);
      t[r + 16 * i][c4 + 0] = v.x;
      t[r + 16 * i][c4 + 1] = v.y;
      t[r + 16 * i][c4 + 2] = v.z;
      t[r + 16 * i][c4 + 3] = v.w;
    }
  }
  __syncthreads();
  {
    const int oc = tid >> 3;
    const int r8 = (tid & 7) * 8;
#pragma unroll
    for (int jp = 0; jp < 2; ++jp) {
      const int ocol = oc + 32 * jp;
      union { bf16x8 v; u16 h[8]; } u;
#pragma unroll
      for (int k = 0; k < 8; ++k) u.h[k] = f2bf(t[r8 + k][ocol]);
      *(bf16x8*)(pout + (size_t)(cb + ocol) * orstride + rb + r8) = u.v;
    }
  }
}

// =========== unified GEMM: TMxTN tile, 64x64 waves, 3-buf, 1 barrier/K-tile,
// counted vmcnt(6), compiler-scheduled ds_read/MFMA interleave.
// MODE 1: h' = bf16(gate*relu(acc+bias)); MODE 2: out f32 (+)= acc (+gate.b2)
// BCH: B K-dim spans per-expert [e][*][HDIM] blocks
template <int TM, int TN, int MODE, int BCH>
__global__ __launch_bounds__(512, 2) void k_gemm(
    const u16* __restrict__ A, int lda,
    const u16* __restrict__ Bt, int ldb,
    const float* __restrict__ bias,
    const float* __restrict__ gate, int ebase,
    void* __restrict__ Cout, int ldc,
    int K, int accum, int ca, int cb, int cgcols) {
  constexpr int WN = TN / 64;
  constexpr int BUFE = (TM + TN) * 64;            // elems per buffer
  __shared__ __align__(16) u16 lds[3 * BUFE];     // 144 KiB
  const int tid = threadIdx.x, lane = tid & 63, wid = tid >> 6;
  const int wm = wid / WN, wn = wid % WN;

  // XCD supertiled ordering: chunk = ca x cb tiles, tn-inner
  const int wg = blockIdx.x;
  const int xcd = wg & 7, lo = wg >> 3;
  const int cr = xcd / cgcols, cc = xcd % cgcols;
  const int tm = cr * ca + lo / cb;
  const int tn = cc * cb + lo % cb;
  const int bm = tm * TM, bn = tn * TN;

  // staging: linear LDS dest + inverse-swizzled global source (rule 21)
  const int srow = tid >> 3;
  const int scol = ((tid & 7) ^ (srow & 7)) << 3;
  const u16* gA = A + (size_t)(bm + srow) * lda + scol;
  const u16* gB = Bt + (size_t)(bn + srow) * ldb + scol;
  const int dofs = wid * 512;

  u16* buf0 = lds;
  u16* buf1 = lds + BUFE;
  u16* buf2 = lds + 2 * BUFE;

#define BOFF(kt) (BCH ? ((size_t)((kt) >> 5) * ((size_t)DDIM * HDIM) +          \
                         (size_t)((kt) & 31) * 64)                              \
                      : (size_t)(kt) * 64)
#define STAGE(dst, kt)                                                          \
  { _Pragma("unroll") for (int c_ = 0; c_ < TM / 64; ++c_)                      \
      GLOAD_LDS16(gA + (size_t)(c_ * 64) * lda + (size_t)(kt) * 64,             \
                  (dst) + c_ * 4096 + dofs);                                    \
    _Pragma("unroll") for (int c_ = 0; c_ < TN / 64; ++c_)                      \
      GLOAD_LDS16(gB + (size_t)(c_ * 64) * ldb + BOFF(kt),                      \
                  (dst) + (TM / 64 + c_) * 4096 + dofs); }

  // fragment read offsets (swizzled)
  const int fr = lane & 15, fq = lane >> 4, xr = fr & 7;
  const int so0 = ((0 + fq) ^ xr) << 3;
  const int so1 = ((4 + fq) ^ xr) << 3;

  f32x4 acc[4][4] = {};
  const int nkt = K >> 6;

  STAGE(buf0, 0);
  STAGE(buf1, 1);
  u16 *bC = buf0, *bN = buf1, *bF = buf2;

#pragma unroll 1
  for (int t = 0; t < nkt; ++t) {
    if (t + 1 < nkt) { asm volatile("s_waitcnt vmcnt(6)" ::: "memory"); }
    else             { asm volatile("s_waitcnt vmcnt(0)" ::: "memory"); }
    __builtin_amdgcn_s_barrier();
    __builtin_amdgcn_sched_barrier(0);
    if (t + 2 < nkt) STAGE(bF, t + 2);
    const u16* aP = bC;
    const u16* bP = bC + TM * 64;
    bf16x8 av[4][2], bv[4][2];
#pragma unroll
    for (int mi = 0; mi < 4; ++mi) {
      const int rb_ = (wm * 64 + mi * 16 + fr) << 6;
      av[mi][0] = *(const bf16x8*)(aP + rb_ + so0);
      av[mi][1] = *(const bf16x8*)(aP + rb_ + so1);
    }
#pragma unroll
    for (int ni = 0; ni < 4; ++ni) {
      const int rb_ = (wn * 64 + ni * 16 + fr) << 6;
      bv[ni][0] = *(const bf16x8*)(bP + rb_ + so0);
      bv[ni][1] = *(const bf16x8*)(bP + rb_ + so1);
    }
    // no forced lgkmcnt(0): compiler interleaves reads with MFMA (fine lgkm waits)
    __builtin_amdgcn_s_setprio(1);
#pragma unroll
    for (int mi = 0; mi < 4; ++mi)
#pragma unroll
      for (int ni = 0; ni < 4; ++ni) {
        acc[mi][ni] = __builtin_amdgcn_mfma_f32_16x16x32_bf16(
            av[mi][0], bv[ni][0], acc[mi][ni], 0, 0, 0);
        acc[mi][ni] = __builtin_amdgcn_mfma_f32_16x16x32_bf16(
            av[mi][1], bv[ni][1], acc[mi][ni], 0, 0, 0);
      }
    __builtin_amdgcn_s_setprio(0);
    u16* tp = bC; bC = bN; bN = bF; bF = tp;
  }

  // ---------------- epilogue; C/D layout: col=lane&15, row=(lane>>4)*4+j
  if (MODE == 1) {
    u16* O = (u16*)Cout;
    const int e = ebase + (bn >> 11);   // TN=128 tile lies within one expert
    float bcol[4];
#pragma unroll
    for (int ni = 0; ni < 4; ++ni) bcol[ni] = bias[bn + wn * 64 + ni * 16 + fr];
#pragma unroll
    for (int mi = 0; mi < 4; ++mi) {
#pragma unroll
      for (int j = 0; j < 4; ++j) {
        const int r = bm + wm * 64 + mi * 16 + fq * 4 + j;
        const float g = gate[(size_t)r * NEXP + e];
#pragma unroll
        for (int ni = 0; ni < 4; ++ni) {
          float v = fmaxf(acc[mi][ni][j] + bcol[ni], 0.f) * g;
          O[(size_t)r * ldc + bn + wn * 64 + ni * 16 + fr] = f2bf(v);
        }
      }
    }
  } else {
    float* O = (float*)Cout;
    float b2c[4][NEXP];
    if (!accum) {
#pragma unroll
      for (int ni = 0; ni < 4; ++ni)
#pragma unroll
        for (int e = 0; e < NEXP; ++e)
          b2c[ni][e] = bias[(size_t)e * DDIM + bn + wn * 64 + ni * 16 + fr];
    }
#pragma unroll
    for (int mi = 0; mi < 4; ++mi) {
#pragma unroll
      for (int j = 0; j < 4; ++j) {
        const int r = bm + wm * 64 + mi * 16 + fq * 4 + j;
        if (!accum) {
          float g8[NEXP];
#pragma unroll
          for (int e = 0; e < NEXP; ++e) g8[e] = gate[(size_t)r * NEXP + e];
#pragma unroll
          for (int ni = 0; ni < 4; ++ni) {
            float v = acc[mi][ni][j];
#pragma unroll
            for (int e = 0; e < NEXP; ++e) v += g8[e] * b2c[ni][e];
            O[(size_t)r * DDIM + bn + wn * 64 + ni * 16 + fr] = v;
          }
        } else {
#pragma unroll
          for (int ni = 0; ni < 4; ++ni) {
            const size_t idx = (size_t)r * DDIM + bn + wn * 64 + ni * 16 + fr;
            O[idx] += acc[mi][ni][j];
          }
        }
      }
    }
  }
#undef STAGE
#undef BOFF
}

extern "C" void kernel_launch(void* const* d_in, const int* in_sizes, int n_in,
                              void* d_out, int out_size, void* d_ws, size_t ws_size,
                              hipStream_t stream) {
  (void)in_sizes; (void)n_in; (void)out_size;
  const float* x  = (const float*)d_in[0];   // [N, D]
  const float* W1 = (const float*)d_in[1];   // [E, D, H]
  const float* b1 = (const float*)d_in[2];   // [E, H]
  const float* W2 = (const float*)d_in[3];   // [E, H, D]
  const float* b2 = (const float*)d_in[4];   // [E, D]
  const float* Wg = (const float*)d_in[5];   // [D, E]
  const float* bg = (const float*)d_in[6];   // [E]
  float* out = (float*)d_out;                // [N, D]

  size_t o_xb   = 0;
  size_t o_w1t  = o_xb  + (size_t)NTOK * DDIM * 2;          // xb   bf16 [N,D]
  size_t o_w2t  = o_w1t + (size_t)NEXP * HDIM * DDIM * 2;   // W1t  bf16 [E*H, D]
  size_t o_gate = o_w2t + (size_t)NEXP * DDIM * HDIM * 2;   // W2t  bf16 [E][D][H]
  size_t o_h    = o_gate + (size_t)NTOK * NEXP * 4;         // gate f32  [N, E]
  size_t need   = o_h   + (size_t)NTOK * GEXP * HDIM * 2;   // h'   bf16 [N, G*H]
  if (ws_size < need) return;

  u16*   xb   = (u16*)((char*)d_ws + o_xb);
  u16*   W1t  = (u16*)((char*)d_ws + o_w1t);
  u16*   W2t  = (u16*)((char*)d_ws + o_w2t);
  float* gate = (float*)((char*)d_ws + o_gate);
  u16*   hbuf = (u16*)((char*)d_ws + o_h);

  k_prep<<<NTOK / 4, 256, 0, stream>>>(x, Wg, bg, xb, gate);
  dim3 g1(DDIM / 64, HDIM / 64, NEXP);
  k_transpose<<<g1, 256, 0, stream>>>(W1, W1t, DDIM, HDIM, (size_t)HDIM * DDIM, DDIM);
  dim3 g2(HDIM / 64, DDIM / 64, NEXP);
  k_transpose<<<g2, 256, 0, stream>>>(W2, W2t, HDIM, DDIM, (size_t)DDIM * HDIM, HDIM);

  const int Ng = GEXP * HDIM;                  // 4096
  for (int g = 0; g < NEXP / GEXP; ++g) {
    // GEMM1: 256x128 tiles, grid 32tm x 32tn = 1024; chunks 16x8, cgcols 4
    k_gemm<256, 128, 1, 0><<<1024, 512, 0, stream>>>(
        xb, DDIM, W1t + (size_t)g * Ng * DDIM, DDIM,
        b1 + (size_t)g * Ng, gate, g * GEXP,
        hbuf, Ng, DDIM, 0, 16, 8, 4);
    // GEMM2: 128x256 tiles, grid 64tm x 4tn = 256; chunks 8x4, cgcols 1
    k_gemm<128, 256, 2, 1><<<256, 512, 0, stream>>>(
        hbuf, Ng, W2t + (size_t)g * GEXP * DDIM * HDIM, HDIM,
        b2, gate, 0,
        out, DDIM, Ng, g > 0, 8, 4, 1);
  }
}